// Round 1
// 281.999 us; speedup vs baseline: 1.1525x; 1.1525x over previous
//
#include <hip/hip_runtime.h>
#include <hip/hip_fp16.h>

#define NN 100000
#define NE 1600000
#define D  64

#define B1    1024         // phase-1 blocks (hist / scatter): 4 blocks per CU
#define BSH   9            // coarse bin = dst >> 9  (512 nodes per bin)
#define BMSK  511
#define NB    196          // ceil(NN / 512)
#define M     (NB * B1)    // hist entries = 200704

// ---------- phase A: per-block coarse histogram (LDS atomics only) ----------
__global__ __launch_bounds__(256) void k_hist(const int* __restrict__ dst,
                                              int* __restrict__ hist) {
    __shared__ int h[NB];
    int t = threadIdx.x, blk = blockIdx.x;
    for (int i = t; i < NB; i += 256) h[i] = 0;
    __syncthreads();
    for (int e = blk * 256 + t; e < NE; e += B1 * 256)
        atomicAdd(&h[dst[e] >> BSH], 1);
    __syncthreads();
    for (int i = t; i < NB; i += 256) hist[i * B1 + blk] = h[i];  // bin-major
}

// ---------- hierarchical scan: per-bin scan over B1 block-counts ----------
__global__ __launch_bounds__(1024) void k_scanA(int* __restrict__ hist,
                                                int* __restrict__ binsum) {
    __shared__ int ps[1024];
    int t = threadIdx.x, b = blockIdx.x;          // b = bin
    int v = hist[b * B1 + t];
    ps[t] = v;
    __syncthreads();
    for (int off = 1; off < 1024; off <<= 1) {
        int u = (t >= off) ? ps[t - off] : 0;
        __syncthreads();
        ps[t] += u;
        __syncthreads();
    }
    hist[b * B1 + t] = ps[t] - v;                 // exclusive within bin
    if (t == 1023) binsum[b] = ps[t];             // bin total
}

// ---------- scan of 196 bin totals (tiny) ----------
__global__ __launch_bounds__(256) void k_scanB(const int* __restrict__ binsum,
                                               int* __restrict__ binoff) {
    __shared__ int ps[256];
    int t = threadIdx.x;
    int v = (t < NB) ? binsum[t] : 0;
    ps[t] = v;
    __syncthreads();
    for (int off = 1; off < 256; off <<= 1) {
        int u = (t >= off) ? ps[t - off] : 0;
        __syncthreads();
        ps[t] += u;
        __syncthreads();
    }
    if (t < NB) binoff[t] = ps[t] - v;            // exclusive bin start
    if (t == NB - 1) binoff[NB] = ps[t];          // == NE
}

// ---------- phase B: scatter packed (src<<9 | local) into bin-contig ebuf ----------
__global__ __launch_bounds__(256) void k_scatter1(
    const int* __restrict__ src, const int* __restrict__ dst,
    const int* __restrict__ hist, const int* __restrict__ binoff,
    unsigned* __restrict__ ebuf)
{
    __shared__ int cur[NB];
    int t = threadIdx.x, blk = blockIdx.x;
    for (int i = t; i < NB; i += 256)
        cur[i] = binoff[i] + hist[i * B1 + blk];
    __syncthreads();
    for (int e = blk * 256 + t; e < NE; e += B1 * 256) {
        int d = dst[e];
        int p = atomicAdd(&cur[d >> BSH], 1);                // LDS atomic
        ebuf[p] = ((unsigned)src[e] << BSH) | (unsigned)(d & BMSK);
    }
}

// ---------- phase C: per-bin exact CSR, all in LDS (one node per thread) ----------
__global__ __launch_bounds__(512) void k_build(
    const int* __restrict__ binoff, const unsigned* __restrict__ ebuf,
    int* __restrict__ rs, float* __restrict__ dinv, int* __restrict__ bucket)
{
    __shared__ int c[512];
    __shared__ int ps[512];
    int t = threadIdx.x, b = blockIdx.x;
    int e0 = binoff[b], e1 = binoff[b + 1];
    c[t] = 0;
    __syncthreads();
    for (int e = e0 + t; e < e1; e += 512)
        atomicAdd(&c[ebuf[e] & BMSK], 1);
    __syncthreads();
    int a = c[t];
    ps[t] = a;
    __syncthreads();
    for (int off = 1; off < 512; off <<= 1) {
        int u = (t >= off) ? ps[t - off] : 0;
        __syncthreads();
        ps[t] += u;
        __syncthreads();
    }
    int p = e0 + ps[t] - a;                       // exclusive row start
    int node = (b << BSH) + t;
    if (node < NN) { rs[node] = p; dinv[node] = rsqrtf((float)(a + 1)); }
    if (b == NB - 1 && t == 0) rs[NN] = NE;
    __syncthreads();
    c[t] = p;                                     // cursors
    __syncthreads();
    for (int e = e0 + t; e < e1; e += 512) {
        unsigned u = ebuf[e];
        int pp = atomicAdd(&c[u & BMSK], 1);      // LDS atomic
        bucket[pp] = (int)(u >> BSH);
    }
}

// ---------- fused GEMMs: blocks [0,half): g = half(x@Wg * dinv)
//                         blocks [half,2*half): out = pos@Wp + bg + bp ----------
__global__ __launch_bounds__(256) void k_mm(
    const float* __restrict__ x, const float* __restrict__ Wg,
    const float* __restrict__ dinv, __half* __restrict__ g,
    const float* __restrict__ pos, const float* __restrict__ Wp,
    const float* __restrict__ bg, const float* __restrict__ bp,
    float* __restrict__ out)
{
    int lane = threadIdx.x & 63;
    int half_grid = gridDim.x >> 1;
    bool job2 = blockIdx.x >= half_grid;
    int blk = job2 ? (blockIdx.x - half_grid) : blockIdx.x;
    int wid = blk * 4 + (threadIdx.x >> 6);
    int nwaves = half_grid * 4;
    const float* A = job2 ? pos : x;
    const float* W = job2 ? Wp : Wg;
    float w[D];
#pragma unroll
    for (int k = 0; k < D; ++k) w[k] = W[k * D + lane];
    float bsum = job2 ? (bg[lane] + bp[lane]) : 0.f;
    for (int n0 = wid; n0 < NN; n0 += nwaves) {
        int n = __builtin_amdgcn_readfirstlane(n0);
        const float4* xr = (const float4*)(A + (long)n * D);
        float acc = 0.f;
#pragma unroll
        for (int k4 = 0; k4 < D / 4; ++k4) {
            float4 v = xr[k4];
            acc = fmaf(v.x, w[4 * k4 + 0], acc);
            acc = fmaf(v.y, w[4 * k4 + 1], acc);
            acc = fmaf(v.z, w[4 * k4 + 2], acc);
            acc = fmaf(v.w, w[4 * k4 + 3], acc);
        }
        if (job2) out[(long)n * D + lane] = acc + bsum;
        else      g[(long)n * D + lane] = __float2half(acc * dinv[n]);
    }
}

// ---------- gather: wave per node, bucket pre-load + 8 rows in flight ----------
__global__ __launch_bounds__(256) void k_gather(
    const int* __restrict__ rs, const int* __restrict__ bucket,
    const float* __restrict__ dinv, const __half* __restrict__ g,
    float* __restrict__ out)
{
    int lane = threadIdx.x & 63;
    int f = lane & 7;                 // 16B granule within 128B row
    int grp = lane >> 3;              // 8 edges processed per wave-instruction
    int w0 = (blockIdx.x << 2) + (threadIdx.x >> 6);
    int nw = gridDim.x << 2;
    const uint4* gq = (const uint4*)g;   // row = 8 uint4 granules

    for (int n0 = w0; n0 < NN; n0 += nw) {
        int node = __builtin_amdgcn_readfirstlane(n0);
        int r0 = rs[node], r1 = rs[node + 1];
        float a0 = 0.f, a1 = 0.f, a2 = 0.f, a3 = 0.f;
        float a4 = 0.f, a5 = 0.f, a6 = 0.f, a7 = 0.f;
        for (int base = r0; base < r1; base += 64) {
            int nl = r1 - base; if (nl > 64) nl = 64;
            int sl = (lane < nl) ? bucket[base + lane] : 0;   // one coalesced load
#pragma unroll 2
            for (int c = 0; c < nl; c += 8) {
                int ei = c + grp;
                int s = __shfl(sl, ei);
                if (ei < nl) {
                    uint4 u = gq[(long)s * 8 + f];
                    __half2 h0 = *(__half2*)&u.x, h1 = *(__half2*)&u.y;
                    __half2 h2 = *(__half2*)&u.z, h3 = *(__half2*)&u.w;
                    a0 += __low2float(h0); a1 += __high2float(h0);
                    a2 += __low2float(h1); a3 += __high2float(h1);
                    a4 += __low2float(h2); a5 += __high2float(h2);
                    a6 += __low2float(h3); a7 += __high2float(h3);
                }
            }
        }
        // reduce across the 8 edge-groups (lane bits 3,4,5)
#pragma unroll
        for (int mask = 8; mask <= 32; mask <<= 1) {
            a0 += __shfl_xor(a0, mask); a1 += __shfl_xor(a1, mask);
            a2 += __shfl_xor(a2, mask); a3 += __shfl_xor(a3, mask);
            a4 += __shfl_xor(a4, mask); a5 += __shfl_xor(a5, mask);
            a6 += __shfl_xor(a6, mask); a7 += __shfl_xor(a7, mask);
        }
        // epilogue: 16 lanes rmw the full 256B out row, fully coalesced
        if (lane < 16) {
            int ff = lane & 7, hs = lane >> 3;
            uint4 u = gq[(long)node * 8 + ff];               // self row granule
            __half2 s0 = hs ? *(__half2*)&u.z : *(__half2*)&u.x;
            __half2 s1 = hs ? *(__half2*)&u.w : *(__half2*)&u.y;
            float b0 = hs ? a4 : a0, b1 = hs ? a5 : a1;
            float b2 = hs ? a6 : a2, b3 = hs ? a7 : a3;
            float di = dinv[node];
            float4* op = (float4*)(out + (long)node * D) + (ff * 2 + hs);
            float4 o = *op;
            o.x += (b0 + __low2float(s0)) * di;
            o.y += (b1 + __high2float(s0)) * di;
            o.z += (b2 + __low2float(s1)) * di;
            o.w += (b3 + __high2float(s1)) * di;
            *op = o;
        }
    }
}

extern "C" void kernel_launch(void* const* d_in, const int* in_sizes, int n_in,
                              void* d_out, int out_size, void* d_ws, size_t ws_size,
                              hipStream_t stream) {
    const float* x   = (const float*)d_in[0];
    const int*   ei  = (const int*)d_in[1];   // [2, NE] int32
    const float* pos = (const float*)d_in[2];
    const float* Wg  = (const float*)d_in[3];
    const float* bg  = (const float*)d_in[4];
    const float* Wp  = (const float*)d_in[5];
    const float* bp  = (const float*)d_in[6];
    float* out = (float*)d_out;

    const int* src = ei;
    const int* dst = ei + NE;

    // ws layout (~25.2 MiB):
    //   bucket[NE]  (hist[M] aliases this region -- temporally disjoint:
    //                hist is dead after k_scatter1; bucket written in k_build)
    //   ebuf[NE] u32 | rs[NN+4] | dinv[NN] | g[NN*D] half | binsum[NB] | binoff[NB+1]
    int*      bucket = (int*)d_ws;
    int*      hist   = (int*)d_ws;                 // alias, see above
    unsigned* ebuf   = (unsigned*)(bucket + NE);
    int*      rs     = (int*)(ebuf + NE);
    float*    dinv   = (float*)(rs + NN + 4);
    __half*   g      = (__half*)(dinv + NN);       // offset 13,600,016: 16B aligned
    int*      binsum = (int*)(g + (size_t)NN * D);
    int*      binoff = binsum + NB;

    hipLaunchKernelGGL(k_hist,     dim3(B1),   dim3(256),  0, stream, dst, hist);
    hipLaunchKernelGGL(k_scanA,    dim3(NB),   dim3(1024), 0, stream, hist, binsum);
    hipLaunchKernelGGL(k_scanB,    dim3(1),    dim3(256),  0, stream, binsum, binoff);
    hipLaunchKernelGGL(k_scatter1, dim3(B1),   dim3(256),  0, stream, src, dst, hist, binoff, ebuf);
    hipLaunchKernelGGL(k_build,    dim3(NB),   dim3(512),  0, stream, binoff, ebuf, rs, dinv, bucket);
    hipLaunchKernelGGL(k_mm,       dim3(2048), dim3(256),  0, stream,
                       x, Wg, dinv, g, pos, Wp, bg, bp, out);
    hipLaunchKernelGGL(k_gather,   dim3(2048), dim3(256),  0, stream,
                       rs, bucket, dinv, g, out);
}

// Round 2
// 215.467 us; speedup vs baseline: 1.5084x; 1.3088x over previous
//
#include <hip/hip_runtime.h>
#include <hip/hip_fp16.h>

#define NN 100000
#define NE 1600000
#define D  64

#define B1    1024         // phase-1 blocks (hist / scatter): 4 blocks per CU
#define BSH   9            // coarse bin = dst >> 9  (512 nodes per bin)
#define BMSK  511
#define NB    196          // ceil(NN / 512)
#define M     (NB * B1)    // hist entries = 200704

typedef __attribute__((ext_vector_type(8))) _Float16 f16x8;
typedef __attribute__((ext_vector_type(4))) float    f32x4;

// ---------- phase A: per-block coarse histogram (LDS atomics only) ----------
__global__ __launch_bounds__(256) void k_hist(const int* __restrict__ dst,
                                              int* __restrict__ hist) {
    __shared__ int h[NB];
    int t = threadIdx.x, blk = blockIdx.x;
    for (int i = t; i < NB; i += 256) h[i] = 0;
    __syncthreads();
    for (int e = blk * 256 + t; e < NE; e += B1 * 256)
        atomicAdd(&h[dst[e] >> BSH], 1);
    __syncthreads();
    for (int i = t; i < NB; i += 256) hist[i * B1 + blk] = h[i];  // bin-major
}

// ---------- hierarchical scan: per-bin scan over B1 block-counts ----------
__global__ __launch_bounds__(1024) void k_scanA(int* __restrict__ hist,
                                                int* __restrict__ binsum) {
    __shared__ int ps[1024];
    int t = threadIdx.x, b = blockIdx.x;          // b = bin
    int v = hist[b * B1 + t];
    ps[t] = v;
    __syncthreads();
    for (int off = 1; off < 1024; off <<= 1) {
        int u = (t >= off) ? ps[t - off] : 0;
        __syncthreads();
        ps[t] += u;
        __syncthreads();
    }
    hist[b * B1 + t] = ps[t] - v;                 // exclusive within bin
    if (t == 1023) binsum[b] = ps[t];             // bin total
}

// ---------- scan of 196 bin totals (tiny) ----------
__global__ __launch_bounds__(256) void k_scanB(const int* __restrict__ binsum,
                                               int* __restrict__ binoff) {
    __shared__ int ps[256];
    int t = threadIdx.x;
    int v = (t < NB) ? binsum[t] : 0;
    ps[t] = v;
    __syncthreads();
    for (int off = 1; off < 256; off <<= 1) {
        int u = (t >= off) ? ps[t - off] : 0;
        __syncthreads();
        ps[t] += u;
        __syncthreads();
    }
    if (t < NB) binoff[t] = ps[t] - v;            // exclusive bin start
    if (t == NB - 1) binoff[NB] = ps[t];          // == NE
}

// ---------- phase B: scatter packed (src<<9 | local) into bin-contig ebuf ----------
__global__ __launch_bounds__(256) void k_scatter1(
    const int* __restrict__ src, const int* __restrict__ dst,
    const int* __restrict__ hist, const int* __restrict__ binoff,
    unsigned* __restrict__ ebuf)
{
    __shared__ int cur[NB];
    int t = threadIdx.x, blk = blockIdx.x;
    for (int i = t; i < NB; i += 256)
        cur[i] = binoff[i] + hist[i * B1 + blk];
    __syncthreads();
    for (int e = blk * 256 + t; e < NE; e += B1 * 256) {
        int d = dst[e];
        int p = atomicAdd(&cur[d >> BSH], 1);                // LDS atomic
        ebuf[p] = ((unsigned)src[e] << BSH) | (unsigned)(d & BMSK);
    }
}

// ---------- phase C: per-bin exact CSR, all in LDS (one node per thread) ----------
__global__ __launch_bounds__(512) void k_build(
    const int* __restrict__ binoff, const unsigned* __restrict__ ebuf,
    int* __restrict__ rs, float* __restrict__ dinv, int* __restrict__ bucket)
{
    __shared__ int c[512];
    __shared__ int ps[512];
    int t = threadIdx.x, b = blockIdx.x;
    int e0 = binoff[b], e1 = binoff[b + 1];
    c[t] = 0;
    __syncthreads();
    for (int e = e0 + t; e < e1; e += 512)
        atomicAdd(&c[ebuf[e] & BMSK], 1);
    __syncthreads();
    int a = c[t];
    ps[t] = a;
    __syncthreads();
    for (int off = 1; off < 512; off <<= 1) {
        int u = (t >= off) ? ps[t - off] : 0;
        __syncthreads();
        ps[t] += u;
        __syncthreads();
    }
    int p = e0 + ps[t] - a;                       // exclusive row start
    int node = (b << BSH) + t;
    if (node < NN) { rs[node] = p; dinv[node] = rsqrtf((float)(a + 1)); }
    if (b == NB - 1 && t == 0) rs[NN] = NE;
    __syncthreads();
    c[t] = p;                                     // cursors
    __syncthreads();
    for (int e = e0 + t; e < e1; e += 512) {
        unsigned u = ebuf[e];
        int pp = atomicAdd(&c[u & BMSK], 1);      // LDS atomic
        bucket[pp] = (int)(u >> BSH);
    }
}

// ---------- fused MFMA GEMMs: blocks [0,half): g = half(x@Wg * dinv)
//                              blocks [half,2*half): out = pos@Wp + bg + bp
// wave = 16 rows x 64 cols; A-frag: row=lane&15, k=(lane>>4)*8+j (contig 16B);
// C/D: col=lane&15, row=(lane>>4)*4+reg ----------
__global__ __launch_bounds__(256) void k_mm(
    const float* __restrict__ x, const float* __restrict__ Wg,
    const float* __restrict__ dinv, __half* __restrict__ g,
    const float* __restrict__ pos, const float* __restrict__ Wp,
    const float* __restrict__ bg, const float* __restrict__ bp,
    float* __restrict__ out)
{
    __shared__ __align__(16) _Float16 Wt[64][64];   // Wt[n][k] = W[k][n]
    int t = threadIdx.x;
    int lane = t & 63;
    int wid = t >> 6;
    int half_grid = gridDim.x >> 1;
    bool job2 = blockIdx.x >= half_grid;
    int blk = job2 ? (blockIdx.x - half_grid) : blockIdx.x;
    const float* A = job2 ? pos : x;
    const float* W = job2 ? Wp : Wg;

    for (int i = t; i < 64 * 64; i += 256) {
        int k = i >> 6, n = i & 63;
        Wt[n][k] = (_Float16)W[i];
    }
    __syncthreads();

    int lr = lane & 15;        // A-row / C-col within tile
    int lg = lane >> 4;        // k-group / C-row-group
    int kofs = lg * 8;

    f16x8 b[4][2];             // hoisted B frags: [col-tile][k-tile]
#pragma unroll
    for (int n = 0; n < 4; ++n)
#pragma unroll
        for (int kt = 0; kt < 2; ++kt)
            b[n][kt] = *(const f16x8*)&Wt[n * 16 + lr][kt * 32 + kofs];

    float bsum[4] = {0.f, 0.f, 0.f, 0.f};
    if (job2) {
#pragma unroll
        for (int n = 0; n < 4; ++n) {
            int c = n * 16 + lr;
            bsum[n] = bg[c] + bp[c];
        }
    }

    for (int rb0 = blk * 64; rb0 < NN; rb0 += half_grid * 64) {
        int rb = rb0 + wid * 16;
        int arow = rb + lr;
        int arc = arow < NN ? arow : NN - 1;
        const float4* ap = (const float4*)(A + (long)arc * 64 + kofs);
        float4 p0 = ap[0], p1 = ap[1], p2 = ap[8], p3 = ap[9];
        f16x8 a0, a1;
        a0[0] = (_Float16)p0.x; a0[1] = (_Float16)p0.y;
        a0[2] = (_Float16)p0.z; a0[3] = (_Float16)p0.w;
        a0[4] = (_Float16)p1.x; a0[5] = (_Float16)p1.y;
        a0[6] = (_Float16)p1.z; a0[7] = (_Float16)p1.w;
        a1[0] = (_Float16)p2.x; a1[1] = (_Float16)p2.y;
        a1[2] = (_Float16)p2.z; a1[3] = (_Float16)p2.w;
        a1[4] = (_Float16)p3.x; a1[5] = (_Float16)p3.y;
        a1[6] = (_Float16)p3.z; a1[7] = (_Float16)p3.w;

        f32x4 z = {0.f, 0.f, 0.f, 0.f};
        f32x4 acc[4] = {z, z, z, z};
#pragma unroll
        for (int n = 0; n < 4; ++n) {
            acc[n] = __builtin_amdgcn_mfma_f32_16x16x32_f16(a0, b[n][0], acc[n], 0, 0, 0);
            acc[n] = __builtin_amdgcn_mfma_f32_16x16x32_f16(a1, b[n][1], acc[n], 0, 0, 0);
        }

        int orow0 = rb + lg * 4;
        if (!job2) {
#pragma unroll
            for (int r = 0; r < 4; ++r) {
                int row = orow0 + r;
                if (row < NN) {
                    float di = dinv[row];
#pragma unroll
                    for (int n = 0; n < 4; ++n)
                        g[(long)row * D + n * 16 + lr] = __float2half(acc[n][r] * di);
                }
            }
        } else {
#pragma unroll
            for (int r = 0; r < 4; ++r) {
                int row = orow0 + r;
                if (row < NN) {
#pragma unroll
                    for (int n = 0; n < 4; ++n)
                        out[(long)row * D + n * 16 + lr] = acc[n][r] + bsum[n];
                }
            }
        }
    }
}

// ---------- gather: wave per node, bucket pre-load + 8 rows in flight ----------
__global__ __launch_bounds__(256) void k_gather(
    const int* __restrict__ rs, const int* __restrict__ bucket,
    const float* __restrict__ dinv, const __half* __restrict__ g,
    float* __restrict__ out)
{
    int lane = threadIdx.x & 63;
    int f = lane & 7;                 // 16B granule within 128B row
    int grp = lane >> 3;              // 8 edges processed per wave-instruction
    int w0 = (blockIdx.x << 2) + (threadIdx.x >> 6);
    int nw = gridDim.x << 2;
    const uint4* gq = (const uint4*)g;   // row = 8 uint4 granules

    for (int n0 = w0; n0 < NN; n0 += nw) {
        int node = __builtin_amdgcn_readfirstlane(n0);
        int r0 = rs[node], r1 = rs[node + 1];
        float a0 = 0.f, a1 = 0.f, a2 = 0.f, a3 = 0.f;
        float a4 = 0.f, a5 = 0.f, a6 = 0.f, a7 = 0.f;
        for (int base = r0; base < r1; base += 64) {
            int nl = r1 - base; if (nl > 64) nl = 64;
            int sl = (lane < nl) ? bucket[base + lane] : 0;   // one coalesced load
#pragma unroll 2
            for (int c = 0; c < nl; c += 8) {
                int ei = c + grp;
                int s = __shfl(sl, ei);
                if (ei < nl) {
                    uint4 u = gq[(long)s * 8 + f];
                    __half2 h0 = *(__half2*)&u.x, h1 = *(__half2*)&u.y;
                    __half2 h2 = *(__half2*)&u.z, h3 = *(__half2*)&u.w;
                    a0 += __low2float(h0); a1 += __high2float(h0);
                    a2 += __low2float(h1); a3 += __high2float(h1);
                    a4 += __low2float(h2); a5 += __high2float(h2);
                    a6 += __low2float(h3); a7 += __high2float(h3);
                }
            }
        }
        // reduce across the 8 edge-groups (lane bits 3,4,5)
#pragma unroll
        for (int mask = 8; mask <= 32; mask <<= 1) {
            a0 += __shfl_xor(a0, mask); a1 += __shfl_xor(a1, mask);
            a2 += __shfl_xor(a2, mask); a3 += __shfl_xor(a3, mask);
            a4 += __shfl_xor(a4, mask); a5 += __shfl_xor(a5, mask);
            a6 += __shfl_xor(a6, mask); a7 += __shfl_xor(a7, mask);
        }
        // epilogue: 16 lanes rmw the full 256B out row, fully coalesced
        if (lane < 16) {
            int ff = lane & 7, hs = lane >> 3;
            uint4 u = gq[(long)node * 8 + ff];               // self row granule
            __half2 s0 = hs ? *(__half2*)&u.z : *(__half2*)&u.x;
            __half2 s1 = hs ? *(__half2*)&u.w : *(__half2*)&u.y;
            float b0 = hs ? a4 : a0, b1 = hs ? a5 : a1;
            float b2 = hs ? a6 : a2, b3 = hs ? a7 : a3;
            float di = dinv[node];
            float4* op = (float4*)(out + (long)node * D) + (ff * 2 + hs);
            float4 o = *op;
            o.x += (b0 + __low2float(s0)) * di;
            o.y += (b1 + __high2float(s0)) * di;
            o.z += (b2 + __low2float(s1)) * di;
            o.w += (b3 + __high2float(s1)) * di;
            *op = o;
        }
    }
}

extern "C" void kernel_launch(void* const* d_in, const int* in_sizes, int n_in,
                              void* d_out, int out_size, void* d_ws, size_t ws_size,
                              hipStream_t stream) {
    const float* x   = (const float*)d_in[0];
    const int*   ei  = (const int*)d_in[1];   // [2, NE] int32
    const float* pos = (const float*)d_in[2];
    const float* Wg  = (const float*)d_in[3];
    const float* bg  = (const float*)d_in[4];
    const float* Wp  = (const float*)d_in[5];
    const float* bp  = (const float*)d_in[6];
    float* out = (float*)d_out;

    const int* src = ei;
    const int* dst = ei + NE;

    // ws layout (~25.2 MiB):
    //   bucket[NE]  (hist[M] aliases this region -- temporally disjoint:
    //                hist is dead after k_scatter1; bucket written in k_build)
    //   ebuf[NE] u32 | rs[NN+4] | dinv[NN] | g[NN*D] half | binsum[NB] | binoff[NB+1]
    int*      bucket = (int*)d_ws;
    int*      hist   = (int*)d_ws;                 // alias, see above
    unsigned* ebuf   = (unsigned*)(bucket + NE);
    int*      rs     = (int*)(ebuf + NE);
    float*    dinv   = (float*)(rs + NN + 4);
    __half*   g      = (__half*)(dinv + NN);       // 16B aligned
    int*      binsum = (int*)(g + (size_t)NN * D);
    int*      binoff = binsum + NB;

    hipLaunchKernelGGL(k_hist,     dim3(B1),   dim3(256),  0, stream, dst, hist);
    hipLaunchKernelGGL(k_scanA,    dim3(NB),   dim3(1024), 0, stream, hist, binsum);
    hipLaunchKernelGGL(k_scanB,    dim3(1),    dim3(256),  0, stream, binsum, binoff);
    hipLaunchKernelGGL(k_scatter1, dim3(B1),   dim3(256),  0, stream, src, dst, hist, binoff, ebuf);
    hipLaunchKernelGGL(k_build,    dim3(NB),   dim3(512),  0, stream, binoff, ebuf, rs, dinv, bucket);
    hipLaunchKernelGGL(k_mm,       dim3(1564), dim3(256),  0, stream,
                       x, Wg, dinv, g, pos, Wp, bg, bp, out);
    hipLaunchKernelGGL(k_gather,   dim3(2048), dim3(256),  0, stream,
                       rs, bucket, dinv, g, out);
}